// Round 4
// baseline (361.932 us; speedup 1.0000x reference)
//
#include <hip/hip_runtime.h>
#include <type_traits>
#include <utility>

typedef unsigned short u16;
typedef unsigned int u32;
typedef short short8 __attribute__((ext_vector_type(8)));
typedef __bf16 bf16x8 __attribute__((ext_vector_type(8)));
typedef float floatx4 __attribute__((ext_vector_type(4)));

// ---- MFMA wrapper robust to either builtin signature (short8 vs v8bf16) ----
template <typename V, typename = void> struct MfmaTakes : std::false_type {};
template <typename V>
struct MfmaTakes<V, std::void_t<decltype(__builtin_amdgcn_mfma_f32_16x16x32_bf16(
    std::declval<V>(), std::declval<V>(), std::declval<floatx4>(), 0, 0, 0))>>
    : std::true_type {};

template <typename V>
__device__ __forceinline__ floatx4 mfma_impl(V a, V b, floatx4 c, std::true_type) {
  return __builtin_amdgcn_mfma_f32_16x16x32_bf16(a, b, c, 0, 0, 0);
}
template <typename V>
__device__ __forceinline__ floatx4 mfma_impl(V a, V b, floatx4 c, std::false_type) {
  return __builtin_amdgcn_mfma_f32_16x16x32_bf16(
      __builtin_bit_cast(bf16x8, a), __builtin_bit_cast(bf16x8, b), c, 0, 0, 0);
}
__device__ __forceinline__ floatx4 MFMA16(short8 a, short8 b, floatx4 c) {
  return mfma_impl<short8>(a, b, c, MfmaTakes<short8>{});
}

__device__ __forceinline__ u16 f2bf(float f) {
  union { float f; unsigned u; } x; x.f = f;
  unsigned r = (x.u + 0x7fffu + ((x.u >> 16) & 1u)) >> 16;
  return (u16)r;
}
__device__ __forceinline__ float bf2f(u16 v) {
  union { unsigned u; float f; } x; x.u = ((unsigned)v) << 16; return x.f;
}
// pack two fp32 into bf16 pair (truncation; consistent num/denom through MFMA)
__device__ __forceinline__ u32 packbf(float lo, float hi) {
  return (__float_as_uint(hi) & 0xffff0000u) | (__float_as_uint(lo) >> 16);
}

// ---------------- prep: x->bf16, concat W->bf16, out_w->bf16, lambda weights
__global__ __launch_bounds__(256) void prep_kernel(
    const float* __restrict__ x, const float* __restrict__ qw,
    const float* __restrict__ kw, const float* __restrict__ vw,
    const float* __restrict__ outw, const float* __restrict__ lam,
    u16* __restrict__ xb, u16* __restrict__ wcat, u16* __restrict__ outwb,
    float* __restrict__ lwbuf) {
  size_t gid = (size_t)blockIdx.x * 256 + threadIdx.x;
  if (gid == 0) {
    float s0 = 1.f / (1.f + expf(-lam[0]));
    float s1 = 1.f / (1.f + expf(-lam[1]));
    float s2 = 1.f / (1.f + expf(-lam[2]));
    float mean = (s0 + s1 + s2) * (1.f / 3.f);
    float d0 = s0 - mean, d1 = s1 - mean, d2 = s2 - mean;
    float var = (d0 * d0 + d1 * d1 + d2 * d2) * (1.f / 3.f);
    float r = rsqrtf(var + 1e-5f);
    lwbuf[0] = d0 * r; lwbuf[1] = d1 * r; lwbuf[2] = d2 * r;
  }
  if (gid < 524288) {  // xb, 4 elems/thread
    float4 v = ((const float4*)x)[gid];
    ushort4 o; o.x = f2bf(v.x); o.y = f2bf(v.y); o.z = f2bf(v.z); o.w = f2bf(v.w);
    ((ushort4*)xb)[gid] = o;
    return;
  }
  size_t g2 = gid - 524288;
  if (g2 < 1572864) {  // wcat rows: [layer][q(1024)|k(512)|v(512)] x 1024 cols
    int col4 = (int)(g2 & 255);
    int n = (int)(g2 >> 8);
    int layer = n >> 11, r = n & 2047;
    const float* srcrow;
    if (r < 1024) srcrow = qw + ((size_t)(layer * 1024 + r) << 10);
    else if (r < 1536) srcrow = kw + ((size_t)(layer * 512 + (r - 1024)) << 10);
    else srcrow = vw + ((size_t)(layer * 512 + (r - 1536)) << 10);
    float4 v = ((const float4*)srcrow)[col4];
    ushort4 o; o.x = f2bf(v.x); o.y = f2bf(v.y); o.z = f2bf(v.z); o.w = f2bf(v.w);
    ((ushort4*)wcat)[g2] = o;
    return;
  }
  size_t g3 = g2 - 1572864;
  if (g3 < 262144) {
    float4 v = ((const float4*)outw)[g3];
    ushort4 o; o.x = f2bf(v.x); o.y = f2bf(v.y); o.z = f2bf(v.z); o.w = f2bf(v.w);
    ((ushort4*)outwb)[g3] = o;
  }
}

// ---------------- GEMM: C[M,N] = A[M,K](bf16) @ Bw[N,K]^T(bf16)
// 64x64 tile, 4 waves x (16 rows x 64 cols). Many blocks -> good overlap at
// this problem scale (r1 evidence: faster than 128-tile here).
__global__ __launch_bounds__(256) void gemm_bt(
    const u16* __restrict__ A, const u16* __restrict__ Bw,
    void* __restrict__ Cp, int N, int K, int obf16) {
  __shared__ u16 As[64][72];
  __shared__ u16 Bs[64][72];
  const int bm = blockIdx.x, bn = blockIdx.y;
  const int tid = threadIdx.x;
  const int wave = tid >> 6, lane = tid & 63;
  const int quad = lane >> 4, l16 = lane & 15;
  const int lr = tid >> 2, lc = (tid & 3) << 4;
  floatx4 acc[4];
#pragma unroll
  for (int i = 0; i < 4; i++) { acc[i][0] = 0.f; acc[i][1] = 0.f; acc[i][2] = 0.f; acc[i][3] = 0.f; }
  const u16* Arow = A + (size_t)(bm * 64 + lr) * K;
  const u16* Brow = Bw + (size_t)(bn * 64 + lr) * K;
  for (int k0 = 0; k0 < K; k0 += 64) {
    __syncthreads();
    *(uint4*)(&As[lr][lc])     = *(const uint4*)(Arow + k0 + lc);
    *(uint4*)(&As[lr][lc + 8]) = *(const uint4*)(Arow + k0 + lc + 8);
    *(uint4*)(&Bs[lr][lc])     = *(const uint4*)(Brow + k0 + lc);
    *(uint4*)(&Bs[lr][lc + 8]) = *(const uint4*)(Brow + k0 + lc + 8);
    __syncthreads();
    const int mrow = wave * 16 + l16;
    short8 a0 = *(const short8*)(&As[mrow][quad * 8]);
    short8 a1 = *(const short8*)(&As[mrow][32 + quad * 8]);
#pragma unroll
    for (int ns = 0; ns < 4; ns++) {
      short8 b0 = *(const short8*)(&Bs[ns * 16 + l16][quad * 8]);
      short8 b1 = *(const short8*)(&Bs[ns * 16 + l16][32 + quad * 8]);
      acc[ns] = MFMA16(a0, b0, acc[ns]);
      acc[ns] = MFMA16(a1, b1, acc[ns]);
    }
  }
  float* Cf = (float*)Cp;
  u16* Cb = (u16*)Cp;
#pragma unroll
  for (int ns = 0; ns < 4; ns++)
#pragma unroll
    for (int r = 0; r < 4; r++) {
      int row = bm * 64 + wave * 16 + quad * 4 + r;
      int col = bn * 64 + ns * 16 + l16;
      if (obf16) Cb[(size_t)row * N + col] = f2bf(acc[ns][r]);
      else Cf[(size_t)row * N + col] = acc[ns][r];
    }
}

// ---------------- fused reshape: RoPE Q (x0.125) + RoPE K + V transpose
__global__ __launch_bounds__(256) void reshape_kernel(
    const u16* __restrict__ qkvb, const float* __restrict__ cosb,
    const float* __restrict__ sinb, u16* __restrict__ qr,
    u16* __restrict__ kr, u16* __restrict__ vtg) {
  __shared__ u16 T[64][72];
  const int bid = blockIdx.x, tid = threadIdx.x;
  union U8 { uint4 v; u16 s[8]; };
  union F8 { float4 v[2]; float f[8]; };
  if (bid < 2304) {
    unsigned gid = (unsigned)bid * 256 + tid;
    if (gid < 393216u) {  // Q: d8(2b) t(10b) h(4b) b(1b) layer
      int d8 = gid & 3, t = (gid >> 2) & 1023, h = (gid >> 12) & 15;
      int b = (gid >> 16) & 1, layer = gid >> 17;
      size_t src = (size_t)(b * 1024 + t) * 6144 + layer * 2048 + h * 64 + d8 * 8;
      U8 xa, xc; xa.v = *(const uint4*)(qkvb + src); xc.v = *(const uint4*)(qkvb + src + 32);
      F8 C, S;
      const float4* cp = (const float4*)(cosb + (size_t)t * 32 + d8 * 8);
      const float4* sp = (const float4*)(sinb + (size_t)t * 32 + d8 * 8);
      C.v[0] = cp[0]; C.v[1] = cp[1]; S.v[0] = sp[0]; S.v[1] = sp[1];
      U8 o1, o2;
#pragma unroll
      for (int j = 0; j < 8; j++) {
        float x1 = bf2f(xa.s[j]), x2 = bf2f(xc.s[j]);
        o1.s[j] = f2bf((x1 * C.f[j] - x2 * S.f[j]) * 0.125f);  // fold HD^-0.5
        o2.s[j] = f2bf((x2 * C.f[j] + x1 * S.f[j]) * 0.125f);
      }
      size_t dst = ((((size_t)layer * 2 + b) * 16 + h) * 1024 + t) * 64 + d8 * 8;
      *(uint4*)(qr + dst) = o1.v;
      *(uint4*)(qr + dst + 32) = o2.v;
      return;
    }
    unsigned g2 = gid - 393216u;
    if (g2 < 196608u) {  // K: d8(2b) t(10b) h(3b) b(1b) layer
      int d8 = g2 & 3, t = (g2 >> 2) & 1023, h = (g2 >> 12) & 7;
      int b = (g2 >> 15) & 1, layer = g2 >> 16;
      int pos = layer * 1024 + t;  // layer-j keys sit at offset j*T
      size_t src = (size_t)(b * 1024 + t) * 6144 + layer * 2048 + 1024 + h * 64 + d8 * 8;
      U8 xa, xc; xa.v = *(const uint4*)(qkvb + src); xc.v = *(const uint4*)(qkvb + src + 32);
      F8 C, S;
      const float4* cp = (const float4*)(cosb + (size_t)pos * 32 + d8 * 8);
      const float4* sp = (const float4*)(sinb + (size_t)pos * 32 + d8 * 8);
      C.v[0] = cp[0]; C.v[1] = cp[1]; S.v[0] = sp[0]; S.v[1] = sp[1];
      U8 o1, o2;
#pragma unroll
      for (int j = 0; j < 8; j++) {
        float x1 = bf2f(xa.s[j]), x2 = bf2f(xc.s[j]);
        o1.s[j] = f2bf(x1 * C.f[j] - x2 * S.f[j]);
        o2.s[j] = f2bf(x2 * C.f[j] + x1 * S.f[j]);
      }
      size_t dst = (((size_t)b * 8 + h) * 3072 + pos) * 64 + d8 * 8;
      *(uint4*)(kr + dst) = o1.v;
      *(uint4*)(kr + dst + 32) = o2.v;
    }
    return;
  }
  // V transpose: [tok][6144] slice -> vt [B][HKV][64][3072]
  const int b2 = bid - 2304;
  const int xt = b2 & 15;
  const int y = b2 >> 4;  // layer*16 | b*8 | h
  const int layer = y >> 4, b = (y >> 3) & 1, h = y & 7;
  const int t0 = xt * 64;
  {
    const int p = tid >> 2, dc = (tid & 3) * 16;
    const u16* src = qkvb + (size_t)(b * 1024 + t0 + p) * 6144 + layer * 2048 + 1536 + h * 64 + dc;
    U8 u0, u1;
    u0.v = *(const uint4*)(src);
    u1.v = *(const uint4*)(src + 8);
#pragma unroll
    for (int j = 0; j < 8; j++) { T[dc + j][p] = u0.s[j]; T[dc + 8 + j][p] = u1.s[j]; }
  }
  __syncthreads();
  {
    const int d = tid >> 2, pc = (tid & 3) * 16;
    u16* dst = vtg + ((size_t)((b * 8 + h) * 64 + d)) * 3072 + layer * 1024 + t0 + pc;
    *(uint4*)(dst) = *(const uint4*)(&T[d][pc]);
    *(uint4*)(dst + 8) = *(const uint4*)(&T[d][pc + 8]);
  }
}

// ---------------- attention v2: 128-q blocks, 32 q per wave, S^T orientation.
// S^T = MFMA(A=K, B=Q) -> lane holds (key=quad*4+r, q=l16): P stores to LDS
// are 2x ds_write_b64 per mt (no scalar-write bank conflicts) and read back
// directly as PV B-operand. O^T = MFMA(A=V^T, B=P); l via ones-MFMA.
// No max-subtraction (scores ~N(0,0.25)); chunked KV, per-chunk output slots.
__global__ __launch_bounds__(256) void attn_v2(
    const u16* __restrict__ qr, const u16* __restrict__ kr,
    const u16* __restrict__ vt, float* __restrict__ obT,
    float* __restrict__ lbufp) {
  __shared__ u16 Kt[64][72];        // [key][d]
  __shared__ u16 Vt[64][72];        // [d][key]
  __shared__ u16 Pw[4][2][16][72];  // [wave][ntile][q][key]
  const unsigned z = blockIdx.z;
  const int lay = (0x012221u >> (z * 4)) & 0xF;  // z: (1,0)(2,0)(2,1)(2,2)(1,1)(0,0)
  const int c   = (0x012100u >> (z * 4)) & 0xF;  // full 16-tile chunks first
  const int qtile = 7 - (int)blockIdx.x;         // heavy partials first
  const int bh = blockIdx.y;
  const int b = bh >> 4, h = bh & 15, hk = h >> 1;
  const int tid = threadIdx.x, wave = tid >> 6, lane = tid & 63;
  const int quad = lane >> 4, l16 = lane & 15;
  const int kt0 = c * 16;
  const int kt1 = (c == lay) ? (lay * 16 + 2 * qtile + 2) : (kt0 + 16);
  const int maskkt = lay * 16 + 2 * qtile;       // kt >= this needs elementwise mask
  const int qeffbase = lay * 1024 + qtile * 128 + wave * 32;  // + nt*16 + l16
  // Q fragments: 32 queries per wave (2 n-tiles), B-operand layout
  const u16* qpb = qr + ((((size_t)lay * 2 + b) * 16 + h) * 1024
                         + qtile * 128 + wave * 32 + l16) * 64 + quad * 8;
  short8 qf[2][2];
  qf[0][0] = *(const short8*)(qpb);
  qf[0][1] = *(const short8*)(qpb + 32);
  qf[1][0] = *(const short8*)(qpb + 1024);
  qf[1][1] = *(const short8*)(qpb + 1056);
  const short8 ones = {16256, 16256, 16256, 16256, 16256, 16256, 16256, 16256};
  floatx4 oacc[2][4];
#pragma unroll
  for (int nt = 0; nt < 2; nt++)
#pragma unroll
    for (int dt = 0; dt < 4; dt++) { oacc[nt][dt][0] = 0.f; oacc[nt][dt][1] = 0.f; oacc[nt][dt][2] = 0.f; oacc[nt][dt][3] = 0.f; }
  floatx4 lacc[2];
  lacc[0][0] = 0.f; lacc[0][1] = 0.f; lacc[0][2] = 0.f; lacc[0][3] = 0.f;
  lacc[1] = lacc[0];
  const int sr = tid >> 2, sc = (tid & 3) << 4;
  const u16* kp = kr + ((size_t)(b * 8 + hk) * 3072 + kt0 * 64 + sr) * 64 + sc;
  const u16* vp = vt + ((size_t)(b * 8 + hk) * 64 + sr) * 3072 + kt0 * 64 + sc;
  for (int kt = kt0; kt < kt1; kt++) {
    __syncthreads();
    *(uint4*)(&Kt[sr][sc])     = *(const uint4*)(kp);
    *(uint4*)(&Kt[sr][sc + 8]) = *(const uint4*)(kp + 8);
    *(uint4*)(&Vt[sr][sc])     = *(const uint4*)(vp);
    *(uint4*)(&Vt[sr][sc + 8]) = *(const uint4*)(vp + 8);
    kp += 4096; vp += 64;
    __syncthreads();
    // S^T = K Q^T : per mt (16 keys), both n-tiles share the K fragment
    floatx4 s[4][2];
#pragma unroll
    for (int mt = 0; mt < 4; mt++) {
      short8 kfa = *(const short8*)(&Kt[mt * 16 + l16][quad * 8]);
      short8 kfb = *(const short8*)(&Kt[mt * 16 + l16][32 + quad * 8]);
#pragma unroll
      for (int nt = 0; nt < 2; nt++) {
        floatx4 zz; zz[0] = 0.f; zz[1] = 0.f; zz[2] = 0.f; zz[3] = 0.f;
        zz = MFMA16(kfa, qf[nt][0], zz);
        zz = MFMA16(kfb, qf[nt][1], zz);
        s[mt][nt] = zz;
      }
    }
    if (kt >= maskkt) {
      const int kb = kt * 64;
#pragma unroll
      for (int mt = 0; mt < 4; mt++)
#pragma unroll
        for (int nt = 0; nt < 2; nt++) {
          int qpos = qeffbase + nt * 16 + l16;
#pragma unroll
          for (int r = 0; r < 4; r++)
            if (kb + mt * 16 + quad * 4 + r > qpos) s[mt][nt][r] = -1e30f;
        }
    }
    // P = exp(S^T) -> bf16 -> Pw[wave][nt][q][key] via b64 stores
#pragma unroll
    for (int mt = 0; mt < 4; mt++)
#pragma unroll
      for (int nt = 0; nt < 2; nt++) {
        float p0 = __expf(s[mt][nt][0]), p1 = __expf(s[mt][nt][1]);
        float p2 = __expf(s[mt][nt][2]), p3 = __expf(s[mt][nt][3]);
        uint2 st; st.x = packbf(p0, p1); st.y = packbf(p2, p3);
        *(uint2*)(&Pw[wave][nt][l16][mt * 16 + quad * 4]) = st;
      }
    // O^T += V^T P ; l += ones-row sums (per-wave region: no barrier)
#pragma unroll
    for (int kc = 0; kc < 2; kc++) {
      short8 pf0 = *(const short8*)(&Pw[wave][0][l16][kc * 32 + quad * 8]);
      short8 pf1 = *(const short8*)(&Pw[wave][1][l16][kc * 32 + quad * 8]);
      lacc[0] = MFMA16(ones, pf0, lacc[0]);
      lacc[1] = MFMA16(ones, pf1, lacc[1]);
#pragma unroll
      for (int dt = 0; dt < 4; dt++) {
        short8 vf = *(const short8*)(&Vt[dt * 16 + l16][kc * 32 + quad * 8]);
        oacc[0][dt] = MFMA16(vf, pf0, oacc[0][dt]);
        oacc[1][dt] = MFMA16(vf, pf1, oacc[1][dt]);
      }
    }
  }
  // write O^T partial (coalesced over t) and l partial
  float* obase = obT + (size_t)(z * 32 + bh) * 65536;  // 64 d x 1024 t
#pragma unroll
  for (int nt = 0; nt < 2; nt++) {
    int t = qtile * 128 + wave * 32 + nt * 16 + l16;
#pragma unroll
    for (int dt = 0; dt < 4; dt++)
#pragma unroll
      for (int r = 0; r < 4; r++) {
        int d = dt * 16 + quad * 4 + r;
        obase[(size_t)d * 1024 + t] = oacc[nt][dt][r];
      }
    if (quad == 0)
      lbufp[(size_t)(z * 32 + bh) * 1024 + t] = lacc[nt][0];
  }
}

// ---------------- fused: slot-sum O^T, /l, per-layer rmsnorm-weighted sum, final
__device__ __forceinline__ float block_sum(float v, float* red) {
  v += __shfl_xor(v, 32); v += __shfl_xor(v, 16); v += __shfl_xor(v, 8);
  v += __shfl_xor(v, 4);  v += __shfl_xor(v, 2);  v += __shfl_xor(v, 1);
  __syncthreads();
  if ((threadIdx.x & 63) == 0) red[threadIdx.x >> 6] = v;
  __syncthreads();
  return red[0] + red[1] + red[2] + red[3];
}

__global__ __launch_bounds__(256) void fused_norm(
    const float* __restrict__ obT, const float* __restrict__ lbufp,
    const float* __restrict__ x, const float* __restrict__ lnw,
    const float* __restrict__ lwbuf, const float* __restrict__ flnw,
    const float* __restrict__ alphap, u16* __restrict__ y) {
  __shared__ float red[4];
  const int row = blockIdx.x, tid = threadIdx.x;  // row = b*1024+t
  const int b = row >> 10, t = row & 1023;
  const int h = tid >> 4, d4 = (tid & 15) * 4;    // elem idx = h*64+d4 = tid*4
  const int bh16 = b * 16 + h;
  float a[4] = {0.f, 0.f, 0.f, 0.f};
  const int nsl[3] = {1, 2, 3};
  const int sl[3][3] = {{5, 0, 0}, {0, 4, 0}, {1, 2, 3}};
#pragma unroll
  for (int l = 0; l < 3; l++) {
    float o0 = 0.f, o1 = 0.f, o2 = 0.f, o3 = 0.f, ls = 0.f;
    for (int si = 0; si < nsl[l]; si++) {
      int z = sl[l][si];
      const float* base = obT + ((size_t)(z * 32 + bh16) * 64 + d4) * 1024 + t;
      o0 += base[0]; o1 += base[1024]; o2 += base[2048]; o3 += base[3072];
      ls += lbufp[(size_t)(z * 32 + bh16) * 1024 + t];
    }
    float linv = 1.f / ls;
    float v0 = o0 * linv, v1 = o1 * linv, v2 = o2 * linv, v3 = o3 * linv;
    float ss = v0 * v0 + v1 * v1 + v2 * v2 + v3 * v3;
    ss = block_sum(ss, red);
    float rstd = rsqrtf(ss * (1.f / 1024.f) + 1e-5f);
    float lw = lwbuf[l];
    float4 w = ((const float4*)(lnw + (size_t)l * 1024))[tid];
    a[0] += v0 * rstd * w.x * lw;
    a[1] += v1 * rstd * w.y * lw;
    a[2] += v2 * rstd * w.z * lw;
    a[3] += v3 * rstd * w.w * lw;
  }
  const float aa = alphap[0];
  float4 xv = ((const float4*)(x + (size_t)row * 1024))[tid];
  float v0 = a[0] + aa * xv.x, v1 = a[1] + aa * xv.y;
  float v2 = a[2] + aa * xv.z, v3 = a[3] + aa * xv.w;
  float ss = v0 * v0 + v1 * v1 + v2 * v2 + v3 * v3;
  ss = block_sum(ss, red);
  float rstd = rsqrtf(ss * (1.f / 1024.f) + 1e-5f);
  float4 fw = ((const float4*)flnw)[tid];
  ushort4 o;
  o.x = f2bf(v0 * rstd * fw.x); o.y = f2bf(v1 * rstd * fw.y);
  o.z = f2bf(v2 * rstd * fw.z); o.w = f2bf(v3 * rstd * fw.w);
  ((ushort4*)(y + (size_t)row * 1024))[tid] = o;
}

extern "C" void kernel_launch(void* const* d_in, const int* in_sizes, int n_in,
                              void* d_out, int out_size, void* d_ws, size_t ws_size,
                              hipStream_t stream) {
  const float* x     = (const float*)d_in[0];
  const float* cosb  = (const float*)d_in[1];
  const float* sinb  = (const float*)d_in[2];
  const float* qw    = (const float*)d_in[3];
  const float* kw    = (const float*)d_in[4];
  const float* vw    = (const float*)d_in[5];
  const float* lnw   = (const float*)d_in[6];
  const float* lam   = (const float*)d_in[7];
  const float* outw  = (const float*)d_in[8];
  const float* flnw  = (const float*)d_in[9];
  const float* alphap= (const float*)d_in[10];
  float* out = (float*)d_out;
  char* ws = (char*)d_ws;
  // workspace (~82.6 MB). Region [0,48MB) is time-shared:
  //   phase 1: xb [0,4M) + wcat [4M,16M) + qkvb [16M,40M)   (prep/gemm/reshape)
  //   phase 2: obT [0,48M)                                   (attn/fused_norm)
  u16*   xb    = (u16*)  (ws + 0);          //  4 MB
  u16*   wcat  = (u16*)  (ws + 4194304);    // 12 MB
  u16*   qkvb  = (u16*)  (ws + 16777216);   // 24 MB
  float* obT   = (float*)(ws + 0);          // 48 MB  [6][32][64][1024] fp32
  u16*   outwb = (u16*)  (ws + 50331648);   //  2 MB
  float* lwbuf = (float*)(ws + 52428800);   //  1 KB
  u16*   qr    = (u16*)  (ws + 52429824);   // 12 MB  [3][2][16][1024][64]
  u16*   kr    = (u16*)  (ws + 65012736);   //  6 MB  [2][8][3072][64]
  u16*   vt    = (u16*)  (ws + 71304192);   //  6 MB  [2][8][64][3072]
  float* lbufp = (float*)(ws + 77595648);   // 768 KB [6][32][1024]
  u16*   yb    = (u16*)  (ws + 78382080);   //  4 MB

  prep_kernel<<<9216, 256, 0, stream>>>(x, qw, kw, vw, outw, lam, xb, wcat, outwb, lwbuf);
  gemm_bt<<<dim3(32, 96), 256, 0, stream>>>(xb, wcat, qkvb, 6144, 1024, 1);
  reshape_kernel<<<3072, 256, 0, stream>>>(qkvb, cosb, sinb, qr, kr, vt);
  attn_v2<<<dim3(8, 32, 6), 256, 0, stream>>>(qr, kr, vt, obT, lbufp);
  fused_norm<<<2048, 256, 0, stream>>>(obT, lbufp, x, lnw, lwbuf, flnw, alphap, yb);
  gemm_bt<<<dim3(32, 16), 256, 0, stream>>>(yb, outwb, out, 1024, 1024, 0);
}